// Round 1
// baseline (822.402 us; speedup 1.0000x reference)
//
#include <hip/hip_runtime.h>
#include <hip/hip_bf16.h>
#include <stdint.h>

// Problem constants
#define D_DIM 512
#define K_CB  4096
#define N_TOK 16384
#define TOPK  8

// Tiling
#define TM 64                    // tokens per workgroup
#define TN 256                   // centroids per chunk
#define NCHUNK (K_CB / TN)       // 16
#define DBLK 64                  // d-slice per staging step
#define NDBLK (D_DIM / DBLK)     // 8
#define KSTEP 16                 // MFMA K
#define NKS (DBLK / KSTEP)       // 4
#define CSTR 72                  // LDS row stride (bf16 elems), 64 + 8 pad (keeps 16B align)
#define SSTR 132                 // score row stride (floats)

typedef __attribute__((ext_vector_type(8)))  short          bf16x8;
typedef __attribute__((ext_vector_type(16))) float          f32x16;
typedef __attribute__((ext_vector_type(8)))  unsigned short us8;

__device__ __forceinline__ unsigned short f2bf(float f) {
    union { float f; unsigned u; } v; v.f = f;
    unsigned r = (v.u + 0x7fffu + ((v.u >> 16) & 1u)) >> 16;  // round-to-nearest-even
    return (unsigned short)r;
}

// xb = bf16(2*x)  (the 2x folds the "2ab" factor into the MFMA); also zeroes loss accum
__global__ void conv_x_kernel(const float* __restrict__ x,
                              unsigned short* __restrict__ xb,
                              float* __restrict__ loss) {
    size_t i = (size_t)blockIdx.x * blockDim.x + threadIdx.x;  // float4 index
    float4 v = ((const float4*)x)[i];
    ushort4 o;
    o.x = f2bf(2.f * v.x); o.y = f2bf(2.f * v.y);
    o.z = f2bf(2.f * v.z); o.w = f2bf(2.f * v.w);
    ((ushort4*)xb)[i] = o;
    if (i == 0) *loss = 0.f;
}

// cbb = bf16(codebook), cnorm = ||c||^2 (fp32).  4096 blocks x 64 threads (1 wave/row).
__global__ void conv_cb_kernel(const float* __restrict__ cb,
                               unsigned short* __restrict__ cbb,
                               float* __restrict__ cnorm) {
    const int row = blockIdx.x;
    const int t = threadIdx.x;
    const float4* p = (const float4*)(cb + (size_t)row * D_DIM) + t * 2;
    float4 a = p[0], b = p[1];
    ushort4 o0, o1;
    o0.x = f2bf(a.x); o0.y = f2bf(a.y); o0.z = f2bf(a.z); o0.w = f2bf(a.w);
    o1.x = f2bf(b.x); o1.y = f2bf(b.y); o1.z = f2bf(b.z); o1.w = f2bf(b.w);
    ushort4* dst = (ushort4*)(cbb + (size_t)row * D_DIM) + t * 2;
    dst[0] = o0; dst[1] = o1;
    float sq = a.x*a.x + a.y*a.y + a.z*a.z + a.w*a.w
             + b.x*b.x + b.y*b.y + b.z*b.z + b.w*b.w;
    #pragma unroll
    for (int off = 32; off > 0; off >>= 1) sq += __shfl_down(sq, off, 64);
    if (t == 0) cnorm[row] = sq;
}

__global__ __launch_bounds__(256) void vq_main_kernel(
    const float* __restrict__ x, const float* __restrict__ cb,
    const unsigned short* __restrict__ xb, const unsigned short* __restrict__ cbb,
    const float* __restrict__ cnorm, float* __restrict__ out,
    float* __restrict__ loss_acc)
{
    __shared__ unsigned short xs[TM * CSTR];         // 9216 B
    __shared__ union {
        unsigned short cs[TN * CSTR];                // 36864 B (GEMM phase)
        struct {                                     // epilogue phase (22528 B)
            float ms[TM * 32];                       // 4 partial top-8 lists per token
            int   mi[TM * 32];
            int   tki[TM * TOPK];
            float tks[TM * TOPK];
            float tkw[TM * TOPK];
        } post;
    } u;
    __shared__ float scores[32 * SSTR];              // 16896 B
    __shared__ float redbuf[4];

    const int t    = threadIdx.x;
    const int lane = t & 63;
    const int w    = t >> 6;          // wave id 0..3
    const int m32  = lane & 31;
    const int half = lane >> 5;       // 0/1 within wave
    const int tok0 = blockIdx.x * TM;

    // private running top-8 (sorted descending; strict > keeps lower-index on ties,
    // matching jax.lax.top_k tie-breaking)
    float ts[TOPK]; int ti[TOPK];
    #pragma unroll
    for (int i = 0; i < TOPK; ++i) { ts[i] = -1e30f; ti[i] = 0x7fffffff; }

    for (int chunk = 0; chunk < NCHUNK; ++chunk) {
        const int cbase = chunk * TN;
        f32x16 acc00, acc01, acc10, acc11;
        #pragma unroll
        for (int i = 0; i < 16; ++i) { acc00[i]=0.f; acc01[i]=0.f; acc10[i]=0.f; acc11[i]=0.f; }

        for (int db = 0; db < NDBLK; ++db) {
            const int dbase = db * DBLK;
            __syncthreads();   // prior frag reads / prior chunk's scan done
            // stage x slice [64 tok][64 d]: 512 x 16B
            #pragma unroll
            for (int i = 0; i < 2; ++i) {
                int idx = i * 256 + t;
                int row = idx >> 3, c8 = idx & 7;
                *(us8*)&xs[row * CSTR + c8 * 8] =
                    *(const us8*)&xb[(size_t)(tok0 + row) * D_DIM + dbase + c8 * 8];
            }
            // stage c slice [256 cent][64 d]: 2048 x 16B
            #pragma unroll
            for (int i = 0; i < 8; ++i) {
                int idx = i * 256 + t;
                int row = idx >> 3, c8 = idx & 7;
                *(us8*)&u.cs[row * CSTR + c8 * 8] =
                    *(const us8*)&cbb[(size_t)(cbase + row) * D_DIM + dbase + c8 * 8];
            }
            __syncthreads();
            // wave w computes 64 tok x 64 cent at cols [w*64, w*64+64)
            #pragma unroll
            for (int ks = 0; ks < NKS; ++ks) {
                const int ko = ks * KSTEP + half * 8;
                bf16x8 a0 = *(const bf16x8*)&xs[m32 * CSTR + ko];
                bf16x8 a1 = *(const bf16x8*)&xs[(32 + m32) * CSTR + ko];
                bf16x8 b0 = *(const bf16x8*)&u.cs[(w * 64 + m32) * CSTR + ko];
                bf16x8 b1 = *(const bf16x8*)&u.cs[(w * 64 + 32 + m32) * CSTR + ko];
                acc00 = __builtin_amdgcn_mfma_f32_32x32x16_bf16(a0, b0, acc00, 0, 0, 0);
                acc01 = __builtin_amdgcn_mfma_f32_32x32x16_bf16(a0, b1, acc01, 0, 0, 0);
                acc10 = __builtin_amdgcn_mfma_f32_32x32x16_bf16(a1, b0, acc10, 0, 0, 0);
                acc11 = __builtin_amdgcn_mfma_f32_32x32x16_bf16(a1, b1, acc11, 0, 0, 0);
            }
        }

        // scores = 2 x.c - ||c||^2 ; staged in 4 rounds (one 32-token half x one 32-col block)
        #pragma unroll
        for (int round = 0; round < 4; ++round) {
            const int ri = round >> 1, ci = round & 1;
            __syncthreads();   // previous round's scan done
            const int gcol = cbase + w * 64 + ci * 32 + m32;
            const float cn = cnorm[gcol];
            f32x16 A = (round == 0) ? acc00 : (round == 1) ? acc01
                     : (round == 2) ? acc10 : acc11;
            #pragma unroll
            for (int r = 0; r < 16; ++r) {
                // C/D layout (verified m74/m101): col=lane&31, row=(r&3)+8*(r>>2)+4*(lane>>5)
                const int row32 = (r & 3) + 8 * (r >> 2) + 4 * half;
                scores[row32 * SSTR + w * 32 + m32] = A[r] - cn;
            }
            __syncthreads();
            // scan: thread owns token==lane (fixed for whole kernel), slice==w
            if ((lane >> 5) == ri) {
                const int tk32 = lane & 31;
                const int gbase = cbase + w * 64 + ci * 32;
                for (int j = 0; j < 32; ++j) {
                    float s = scores[tk32 * SSTR + w * 32 + j];
                    if (s > ts[TOPK - 1]) {
                        int gi = gbase + j;
                        #pragma unroll
                        for (int q = 0; q < TOPK; ++q) {
                            if (s > ts[q]) {
                                float tf = ts[q]; ts[q] = s; s = tf;
                                int   tq = ti[q]; ti[q] = gi; gi = tq;
                            }
                        }
                    }
                }
            }
        }
    }

    // ---- epilogue ----
    __syncthreads();
    {   // dump 4 partial lists per token into (freed) cs region
        const int token = lane;
        #pragma unroll
        for (int e = 0; e < TOPK; ++e) {
            u.post.ms[token * 32 + w * 8 + e] = ts[e];
            u.post.mi[token * 32 + w * 8 + e] = ti[e];
        }
    }
    __syncthreads();
    if (t < TM) {   // 4-way merge of sorted lists, tie -> lower index
        int p0 = 0, p1 = 0, p2 = 0, p3 = 0;
        #pragma unroll 1
        for (int r = 0; r < TOPK; ++r) {
            float b_ = -1e38f; int bi = 0x7fffffff; int bl = 0;
            { float s0 = u.post.ms[t*32 +      p0]; int j0 = u.post.mi[t*32 +      p0];
              if (s0 > b_ || (s0 == b_ && j0 < bi)) { b_=s0; bi=j0; bl=0; } }
            { float s1 = u.post.ms[t*32 +  8 + p1]; int j1 = u.post.mi[t*32 +  8 + p1];
              if (s1 > b_ || (s1 == b_ && j1 < bi)) { b_=s1; bi=j1; bl=1; } }
            { float s2 = u.post.ms[t*32 + 16 + p2]; int j2 = u.post.mi[t*32 + 16 + p2];
              if (s2 > b_ || (s2 == b_ && j2 < bi)) { b_=s2; bi=j2; bl=2; } }
            { float s3 = u.post.ms[t*32 + 24 + p3]; int j3 = u.post.mi[t*32 + 24 + p3];
              if (s3 > b_ || (s3 == b_ && j3 < bi)) { b_=s3; bi=j3; bl=3; } }
            if (bl == 0) p0++; else if (bl == 1) p1++; else if (bl == 2) p2++; else p3++;
            u.post.tki[t * TOPK + r] = bi;
        }
    }
    __syncthreads();
    {   // exact fp32 rescore of the 8 selected (kills bf16 weight error)
        const int token = t >> 2, sub = t & 3;
        const float4* xr = (const float4*)(x + (size_t)(tok0 + token) * D_DIM);
        #pragma unroll
        for (int e2 = 0; e2 < 2; ++e2) {
            const int e = sub + e2 * 4;
            const int idx = u.post.tki[token * TOPK + e];
            const float4* cr = (const float4*)(cb + (size_t)idx * D_DIM);
            float dot = 0.f;
            #pragma unroll 4
            for (int i = 0; i < D_DIM / 4; ++i) {
                float4 xv = xr[i], cv = cr[i];
                dot += xv.x*cv.x + xv.y*cv.y + xv.z*cv.z + xv.w*cv.w;
            }
            u.post.tks[token * TOPK + e] = 2.f * dot - cnorm[idx];
        }
    }
    __syncthreads();
    if (t < TM) {   // softmax over the 8 (== renormalized full softmax restricted to top-8)
        float m = -1e38f;
        #pragma unroll
        for (int e = 0; e < TOPK; ++e) m = fmaxf(m, u.post.tks[t*TOPK+e]);
        float sum = 0.f, wv[TOPK];
        #pragma unroll
        for (int e = 0; e < TOPK; ++e) { wv[e] = __expf(u.post.tks[t*TOPK+e] - m); sum += wv[e]; }
        const float inv = 1.f / sum;
        #pragma unroll
        for (int e = 0; e < TOPK; ++e) u.post.tkw[t*TOPK+e] = wv[e] * inv;
    }
    __syncthreads();
    // output + loss partial
    float lsum = 0.f;
    #pragma unroll 1
    for (int it = 0; it < (TM * (D_DIM / 4)) / 256; ++it) {   // 32 iters
        const int p = it * 256 + t;
        const int token = p >> 7, d4 = p & 127;
        float4 q = {0.f, 0.f, 0.f, 0.f};
        #pragma unroll
        for (int e = 0; e < TOPK; ++e) {
            const float wv = u.post.tkw[token * TOPK + e];
            const int  idx = u.post.tki[token * TOPK + e];
            const float4 cv = ((const float4*)cb)[(size_t)idx * (D_DIM / 4) + d4];
            q.x += wv * cv.x; q.y += wv * cv.y; q.z += wv * cv.z; q.w += wv * cv.w;
        }
        const size_t go = (size_t)(tok0 + token) * (D_DIM / 4) + d4;
        const float4 xv = ((const float4*)x)[go];
        const float ex = q.x - xv.x, ey = q.y - xv.y, ez = q.z - xv.z, ew = q.w - xv.w;
        lsum += ex*ex + ey*ey + ez*ez + ew*ew;
        ((float4*)out)[go] = q;   // STE output == quantized value
    }
    #pragma unroll
    for (int off = 32; off > 0; off >>= 1) lsum += __shfl_down(lsum, off, 64);
    if (lane == 0) redbuf[w] = lsum;
    __syncthreads();
    if (t == 0) atomicAdd(loss_acc, redbuf[0] + redbuf[1] + redbuf[2] + redbuf[3]);
}

__global__ void finalize_kernel(const float* __restrict__ loss_acc,
                                float* __restrict__ out) {
    // loss = (1 + COMMITMENT_COST) * mean((q-x)^2)
    out[(size_t)N_TOK * D_DIM] = 1.25f * loss_acc[0] / (float)((size_t)N_TOK * D_DIM);
}

extern "C" void kernel_launch(void* const* d_in, const int* in_sizes, int n_in,
                              void* d_out, int out_size, void* d_ws, size_t ws_size,
                              hipStream_t stream) {
    const float* x  = (const float*)d_in[0];   // [8,2048,512] fp32
    const float* cb = (const float*)d_in[1];   // [4096,512] fp32
    float* out = (float*)d_out;                // [8*2048*512] quantized + [1] loss

    char* ws = (char*)d_ws;
    unsigned short* xb    = (unsigned short*)ws;                          // 16 MB
    unsigned short* cbb   = (unsigned short*)(ws + 16777216);             // 4 MB
    float*          cnorm = (float*)(ws + 16777216 + 4194304);            // 16 KB
    float*          loss  = (float*)(ws + 16777216 + 4194304 + 16384);    // 4 B

    conv_x_kernel<<<8192, 256, 0, stream>>>(x, xb, loss);
    conv_cb_kernel<<<4096, 64, 0, stream>>>(cb, cbb, cnorm);
    vq_main_kernel<<<N_TOK / TM, 256, 0, stream>>>(x, cb, xb, cbb, cnorm, out, loss);
    finalize_kernel<<<1, 1, 0, stream>>>(loss, out);
}

// Round 2
// 700.597 us; speedup vs baseline: 1.1739x; 1.1739x over previous
//
#include <hip/hip_runtime.h>
#include <hip/hip_bf16.h>
#include <stdint.h>

// Problem constants
#define D_DIM 512
#define K_CB  4096
#define N_TOK 16384
#define TOPK  8

// Kernel A tiling: one (64-token tile) x (256-centroid chunk) per block
#define TM 64
#define TN 256
#define NCHUNK (K_CB / TN)       // 16
#define DBLK 64
#define NDBLK (D_DIM / DBLK)     // 8

// Kernel B: 32 tokens per block
#define BTOK 32

typedef __attribute__((ext_vector_type(8)))  short bf16x8;
typedef __attribute__((ext_vector_type(16))) float f32x16;

__device__ __forceinline__ unsigned short f2bf(float f) {
    union { float f; unsigned u; } v; v.f = f;
    unsigned r = (v.u + 0x7fffu + ((v.u >> 16) & 1u)) >> 16;  // RNE, same as round 1
    return (unsigned short)r;
}

// strict-> sorted-desc insertion; ascending-index feed order => jax tie-break (lower idx wins)
__device__ __forceinline__ void ins8(float s, int gi, float (&ts)[8], int (&ti)[8]) {
    if (s > ts[7]) {
        #pragma unroll
        for (int q = 0; q < 8; ++q) {
            if (s > ts[q]) {
                float tf = ts[q]; ts[q] = s; s = tf;
                int   tq = ti[q]; ti[q] = gi; gi = tq;
            }
        }
    }
}

__device__ __forceinline__ void init8(float (&ts)[8], int (&ti)[8]) {
    #pragma unroll
    for (int i = 0; i < 8; ++i) { ts[i] = -1e30f; ti[i] = 0x7fffffff; }
}

__device__ __forceinline__ void gl_lds16(const void* g, void* l) {
    __builtin_amdgcn_global_load_lds(
        (const __attribute__((address_space(1))) void*)g,
        (__attribute__((address_space(3))) void*)l, 16, 0, 0);
}

// cbb = bf16(codebook), cnorm = ||c||^2 (fp32); block 0 zeroes loss accum.
__global__ void conv_cb_kernel(const float* __restrict__ cb,
                               unsigned short* __restrict__ cbb,
                               float* __restrict__ cnorm,
                               float* __restrict__ loss) {
    const int row = blockIdx.x;
    const int t = threadIdx.x;
    if (row == 0 && t == 0) *loss = 0.f;
    const float4* p = (const float4*)(cb + (size_t)row * D_DIM) + t * 2;
    float4 a = p[0], b = p[1];
    ushort4 o0, o1;
    o0.x = f2bf(a.x); o0.y = f2bf(a.y); o0.z = f2bf(a.z); o0.w = f2bf(a.w);
    o1.x = f2bf(b.x); o1.y = f2bf(b.y); o1.z = f2bf(b.z); o1.w = f2bf(b.w);
    ushort4* dst = (ushort4*)(cbb + (size_t)row * D_DIM) + t * 2;
    dst[0] = o0; dst[1] = o1;
    float sq = a.x*a.x + a.y*a.y + a.z*a.z + a.w*a.w
             + b.x*b.x + b.y*b.y + b.z*b.z + b.w*b.w;
    #pragma unroll
    for (int off = 32; off > 0; off >>= 1) sq += __shfl_down(sq, off, 64);
    if (t == 0) cnorm[row] = sq;
}

// Kernel A: per (tile, chunk) block: scores GEMM + per-token top-8 candidates of this chunk.
// LDS layout: XOR-swizzled (slot granule gp holds global granule gp ^ (row&7), row stride 64 bf16)
// => conflict-free b128 staging writes AND fragment reads; lane-linear for global_load_lds.
__global__ __launch_bounds__(256) void vq_gemm_topk(
    const float* __restrict__ x, const unsigned short* __restrict__ cbb,
    const float* __restrict__ cnorm, float* __restrict__ candS,
    unsigned short* __restrict__ candI)
{
    __shared__ union {
        struct { unsigned short xs[TM * DBLK]; unsigned short cs[TN * DBLK]; } st; // 40960 B
        float sc[32 * 257];                                                        // 32896 B
        struct { float msc[64 * 65]; int mid[64 * 65]; } mg;                       // 33280 B
    } u;

    const int t    = threadIdx.x;
    const int lane = t & 63;
    const int w    = t >> 6;
    const int m32  = lane & 31;
    const int half = lane >> 5;
    const int tile = blockIdx.x, chunk = blockIdx.y;
    const int tok0 = tile * TM, cbase = chunk * TN;

    // cnorm for this lane's two column blocks (col = lane&31 in C/D layout)
    const float cn0 = cnorm[cbase + w * 64 + m32];
    const float cn1 = cnorm[cbase + w * 64 + 32 + m32];

    f32x16 acc00, acc01, acc10, acc11;
    #pragma unroll
    for (int i = 0; i < 16; ++i) { acc00[i]=0.f; acc01[i]=0.f; acc10[i]=0.f; acc11[i]=0.f; }

    for (int db = 0; db < NDBLK; ++db) {
        const int dbase = db * DBLK;
        __syncthreads();   // prior frag reads done
        // codebook slice [256][64] via async global->LDS (issue first; DMA overlaps x convert)
        #pragma unroll
        for (int i = 0; i < 8; ++i) {
            const int s = i * 256 + t, row = s >> 3, gp = s & 7;
            const int g = gp ^ (row & 7);
            gl_lds16(&cbb[(size_t)(cbase + row) * D_DIM + dbase + g * 8], &u.st.cs[s * 8]);
        }
        // x slice [64][64]: fp32 load + inline bf16(2x) convert + swizzled ds_write_b128
        #pragma unroll
        for (int i = 0; i < 2; ++i) {
            const int s = i * 256 + t, row = s >> 3, gp = s & 7;
            const int g = gp ^ (row & 7);
            const float4* src = (const float4*)&x[(size_t)(tok0 + row) * D_DIM + dbase + g * 8];
            float4 v0 = src[0], v1 = src[1];
            ushort4 o0, o1;
            o0.x = f2bf(2.f*v0.x); o0.y = f2bf(2.f*v0.y); o0.z = f2bf(2.f*v0.z); o0.w = f2bf(2.f*v0.w);
            o1.x = f2bf(2.f*v1.x); o1.y = f2bf(2.f*v1.y); o1.z = f2bf(2.f*v1.z); o1.w = f2bf(2.f*v1.w);
            *(ushort4*)&u.st.xs[s * 8]     = o0;
            *(ushort4*)&u.st.xs[s * 8 + 4] = o1;
        }
        __syncthreads();   // drains vmcnt (global_load_lds) + lgkmcnt
        #pragma unroll
        for (int ks = 0; ks < 4; ++ks) {
            const int gsw = ((ks * 2 + half) ^ (m32 & 7)) * 8;  // (row&7) == (m32&7) for all 4 rows
            bf16x8 a0 = *(const bf16x8*)&u.st.xs[m32 * 64 + gsw];
            bf16x8 a1 = *(const bf16x8*)&u.st.xs[(32 + m32) * 64 + gsw];
            bf16x8 b0 = *(const bf16x8*)&u.st.cs[(w * 64 + m32) * 64 + gsw];
            bf16x8 b1 = *(const bf16x8*)&u.st.cs[(w * 64 + 32 + m32) * 64 + gsw];
            acc00 = __builtin_amdgcn_mfma_f32_32x32x16_bf16(a0, b0, acc00, 0, 0, 0);
            acc01 = __builtin_amdgcn_mfma_f32_32x32x16_bf16(a0, b1, acc01, 0, 0, 0);
            acc10 = __builtin_amdgcn_mfma_f32_32x32x16_bf16(a1, b0, acc10, 0, 0, 0);
            acc11 = __builtin_amdgcn_mfma_f32_32x32x16_bf16(a1, b1, acc11, 0, 0, 0);
        }
    }

    // ---- score rounds: row-half 0 (tokens 0..31) then row-half 1 (tokens 32..63) ----
    const int srow = t & 31, ssub = t >> 5;   // scan ownership: token row srow, col block ssub
    float l0s[8], l1s[8]; int l0i[8], l1i[8];

    // round 0
    __syncthreads();   // all MFMAs done; stage region reused for scores
    #pragma unroll
    for (int r = 0; r < 16; ++r) {
        const int row32 = (r & 3) + 8 * (r >> 2) + 4 * half;   // C/D layout (m74/m101)
        u.sc[row32 * 257 + w * 64 + m32]      = acc00[r] - cn0;
        u.sc[row32 * 257 + w * 64 + 32 + m32] = acc01[r] - cn1;
    }
    __syncthreads();
    init8(l0s, l0i);
    for (int j = 0; j < 32; ++j)
        ins8(u.sc[srow * 257 + ssub * 32 + j], cbase + ssub * 32 + j, l0s, l0i);

    // round 1
    __syncthreads();
    #pragma unroll
    for (int r = 0; r < 16; ++r) {
        const int row32 = (r & 3) + 8 * (r >> 2) + 4 * half;
        u.sc[row32 * 257 + w * 64 + m32]      = acc10[r] - cn0;
        u.sc[row32 * 257 + w * 64 + 32 + m32] = acc11[r] - cn1;
    }
    __syncthreads();
    init8(l1s, l1i);
    for (int j = 0; j < 32; ++j)
        ins8(u.sc[srow * 257 + ssub * 32 + j], cbase + ssub * 32 + j, l1s, l1i);

    // ---- dump 8 partial lists per token, merge to chunk top-8, emit candidates ----
    __syncthreads();
    #pragma unroll
    for (int e = 0; e < 8; ++e) {
        u.mg.msc[srow * 65 + ssub * 8 + e]        = l0s[e];
        u.mg.mid[srow * 65 + ssub * 8 + e]        = l0i[e];
        u.mg.msc[(32 + srow) * 65 + ssub * 8 + e] = l1s[e];
        u.mg.mid[(32 + srow) * 65 + ssub * 8 + e] = l1i[e];
    }
    __syncthreads();
    if (t < 64) {
        float bs[8]; int bi[8]; init8(bs, bi);
        // lists ordered by ssub asc (=> global idx asc across lists), entries score-desc
        #pragma unroll 4
        for (int k = 0; k < 64; ++k)
            ins8(u.mg.msc[t * 65 + k], u.mg.mid[t * 65 + k], bs, bi);
        const size_t base = ((size_t)(tok0 + t) * NCHUNK + chunk) * TOPK;
        #pragma unroll
        for (int r = 0; r < TOPK; ++r) {
            candS[base + r] = bs[r];
            candI[base + r] = (unsigned short)bi[r];
        }
    }
}

// Kernel B: merge 16 chunks' candidates -> global top-8, exact fp32 rescore, softmax,
// gather-weighted output + loss.
__global__ __launch_bounds__(256) void vq_merge_final(
    const float* __restrict__ x, const float* __restrict__ cb,
    const float* __restrict__ cnorm, const float* __restrict__ candS,
    const unsigned short* __restrict__ candI, float* __restrict__ out,
    float* __restrict__ loss_acc)
{
    __shared__ float pms[BTOK * 65];
    __shared__ int   pmi[BTOK * 65];
    __shared__ int   tki[BTOK * TOPK];
    __shared__ float tks[BTOK * TOPK];
    __shared__ float tkw[BTOK * TOPK];
    __shared__ float redbuf[4];

    const int t = threadIdx.x, lane = t & 63, w = t >> 6;
    const int tok0 = blockIdx.x * BTOK;

    {   // phase 1: 8 threads/token, each merges 2 chunks (16 entries, chunk asc => idx asc)
        const int token = t >> 3, sub = t & 7;
        float ps[8]; int pi[8]; init8(ps, pi);
        const size_t c0 = ((size_t)(tok0 + token) * NCHUNK + sub * 2) * TOPK;
        for (int k = 0; k < 16; ++k)
            ins8(candS[c0 + k], (int)candI[c0 + k], ps, pi);
        #pragma unroll
        for (int e = 0; e < 8; ++e) {
            pms[token * 65 + sub * 8 + e] = ps[e];
            pmi[token * 65 + sub * 8 + e] = pi[e];
        }
    }
    __syncthreads();
    if (t < BTOK) {   // phase 2: 8-list merge -> global top-8 indices
        float bs[8]; int bi[8]; init8(bs, bi);
        #pragma unroll 4
        for (int k = 0; k < 64; ++k)
            ins8(pms[t * 65 + k], pmi[t * 65 + k], bs, bi);
        #pragma unroll
        for (int r = 0; r < TOPK; ++r) tki[t * TOPK + r] = bi[r];
    }
    __syncthreads();
    {   // phase 3: exact fp32 rescore, one (token, entry) dot per thread
        const int token = t >> 3, e = t & 7;
        const int idx = tki[token * TOPK + e];
        const float4* xr = (const float4*)(x + (size_t)(tok0 + token) * D_DIM);
        const float4* cr = (const float4*)(cb + (size_t)idx * D_DIM);
        float dot = 0.f;
        #pragma unroll 4
        for (int i = 0; i < D_DIM / 4; ++i) {
            float4 xv = xr[i], cv = cr[i];
            dot += xv.x*cv.x + xv.y*cv.y + xv.z*cv.z + xv.w*cv.w;
        }
        tks[token * TOPK + e] = 2.f * dot - cnorm[idx];
    }
    __syncthreads();
    if (t < BTOK) {   // phase 4: softmax over 8
        float m = -1e38f;
        #pragma unroll
        for (int e = 0; e < TOPK; ++e) m = fmaxf(m, tks[t*TOPK+e]);
        float sum = 0.f, wv[TOPK];
        #pragma unroll
        for (int e = 0; e < TOPK; ++e) { wv[e] = __expf(tks[t*TOPK+e] - m); sum += wv[e]; }
        const float inv = 1.f / sum;
        #pragma unroll
        for (int e = 0; e < TOPK; ++e) tkw[t*TOPK+e] = wv[e] * inv;
    }
    __syncthreads();
    // phase 5: output + loss partial
    float lsum = 0.f;
    #pragma unroll 1
    for (int it = 0; it < (BTOK * (D_DIM / 4)) / 256; ++it) {   // 16 iters
        const int p = it * 256 + t;
        const int token = p >> 7, d4 = p & 127;
        float4 q = {0.f, 0.f, 0.f, 0.f};
        #pragma unroll
        for (int e = 0; e < TOPK; ++e) {
            const float wv = tkw[token * TOPK + e];
            const int  idx = tki[token * TOPK + e];
            const float4 cv = ((const float4*)cb)[(size_t)idx * (D_DIM / 4) + d4];
            q.x += wv * cv.x; q.y += wv * cv.y; q.z += wv * cv.z; q.w += wv * cv.w;
        }
        const size_t go = (size_t)(tok0 + token) * (D_DIM / 4) + d4;
        const float4 xv = ((const float4*)x)[go];
        const float ex = q.x - xv.x, ey = q.y - xv.y, ez = q.z - xv.z, ew = q.w - xv.w;
        lsum += ex*ex + ey*ey + ez*ez + ew*ew;
        ((float4*)out)[go] = q;
    }
    #pragma unroll
    for (int off = 32; off > 0; off >>= 1) lsum += __shfl_down(lsum, off, 64);
    if (lane == 0) redbuf[w] = lsum;
    __syncthreads();
    if (t == 0) atomicAdd(loss_acc, redbuf[0] + redbuf[1] + redbuf[2] + redbuf[3]);
}

__global__ void finalize_kernel(const float* __restrict__ loss_acc,
                                float* __restrict__ out) {
    out[(size_t)N_TOK * D_DIM] = 1.25f * loss_acc[0] / (float)((size_t)N_TOK * D_DIM);
}

extern "C" void kernel_launch(void* const* d_in, const int* in_sizes, int n_in,
                              void* d_out, int out_size, void* d_ws, size_t ws_size,
                              hipStream_t stream) {
    const float* x  = (const float*)d_in[0];   // [8,2048,512] fp32
    const float* cb = (const float*)d_in[1];   // [4096,512] fp32
    float* out = (float*)d_out;

    char* ws = (char*)d_ws;
    unsigned short* cbb   = (unsigned short*)ws;                     // 4 MB
    float*          cnorm = (float*)(ws + 4194304);                  // 16 KB
    float*          loss  = (float*)(ws + 4210688);                  // 64 B pad
    float*          candS = (float*)(ws + 4210752);                  // 8 MB
    unsigned short* candI = (unsigned short*)(ws + 12599360);        // 4 MB
    // total ws use ~16.1 MB (round 1 used 21 MB successfully)

    conv_cb_kernel<<<4096, 64, 0, stream>>>(cb, cbb, cnorm, loss);
    vq_gemm_topk<<<dim3(256, 16), 256, 0, stream>>>(x, cbb, cnorm, candS, candI);
    vq_merge_final<<<N_TOK / BTOK, 256, 0, stream>>>(x, cb, cnorm, candS, candI, out, loss);
    finalize_kernel<<<1, 1, 0, stream>>>(loss, out);
}

// Round 3
// 486.036 us; speedup vs baseline: 1.6921x; 1.4415x over previous
//
#include <hip/hip_runtime.h>
#include <hip/hip_bf16.h>
#include <stdint.h>

// Problem constants
#define D_DIM 512
#define K_CB  4096
#define N_TOK 16384
#define TOPK  8

// Fused kernel tiling: 32 tokens x full 4096 centroids per block
#define TOKB 32
#define TN   256                 // centroid chunk
#define NCHUNK (K_CB / TN)       // 16
#define DBLK 64
#define NDBLK (D_DIM / DBLK)     // 8

typedef __attribute__((ext_vector_type(8)))  short bf16x8;
typedef __attribute__((ext_vector_type(16))) float f32x16;

__device__ __forceinline__ unsigned short f2bf(float f) {
    union { float f; unsigned u; } v; v.f = f;
    unsigned r = (v.u + 0x7fffu + ((v.u >> 16) & 1u)) >> 16;  // RNE, same as rounds 1-2
    return (unsigned short)r;
}

// strict-> sorted-desc insertion; ascending-index feed order => jax tie-break (lower idx wins)
__device__ __forceinline__ void ins8(float s, int gi, float (&ts)[8], int (&ti)[8]) {
    if (s > ts[7]) {
        #pragma unroll
        for (int q = 0; q < 8; ++q) {
            if (s > ts[q]) {
                float tf = ts[q]; ts[q] = s; s = tf;
                int   tq = ti[q]; ti[q] = gi; gi = tq;
            }
        }
    }
}

__device__ __forceinline__ void init8(float (&ts)[8], int (&ti)[8]) {
    #pragma unroll
    for (int i = 0; i < 8; ++i) { ts[i] = -1e30f; ti[i] = 0x7fffffff; }
}

__device__ __forceinline__ void gl_lds16(const void* g, void* l) {
    __builtin_amdgcn_global_load_lds(
        (const __attribute__((address_space(1))) void*)g,
        (__attribute__((address_space(3))) void*)l, 16, 0, 0);
}

// cbb = bf16(codebook), cnorm = ||c||^2 (fp32); block 0 zeroes loss accum.
__global__ void conv_cb_kernel(const float* __restrict__ cb,
                               unsigned short* __restrict__ cbb,
                               float* __restrict__ cnorm,
                               float* __restrict__ loss) {
    const int row = blockIdx.x;
    const int t = threadIdx.x;
    if (row == 0 && t == 0) *loss = 0.f;
    const float4* p = (const float4*)(cb + (size_t)row * D_DIM) + t * 2;
    float4 a = p[0], b = p[1];
    ushort4 o0, o1;
    o0.x = f2bf(a.x); o0.y = f2bf(a.y); o0.z = f2bf(a.z); o0.w = f2bf(a.w);
    o1.x = f2bf(b.x); o1.y = f2bf(b.y); o1.z = f2bf(b.z); o1.w = f2bf(b.w);
    ushort4* dst = (ushort4*)(cbb + (size_t)row * D_DIM) + t * 2;
    dst[0] = o0; dst[1] = o1;
    float sq = a.x*a.x + a.y*a.y + a.z*a.z + a.w*a.w
             + b.x*b.x + b.y*b.y + b.z*b.z + b.w*b.w;
    #pragma unroll
    for (int off = 32; off > 0; off >>= 1) sq += __shfl_down(sq, off, 64);
    if (t == 0) cnorm[row] = sq;
}

// Fused: per block (32 tokens): full-K scores GEMM + persistent top-8 selection +
// exact fp32 rescore + softmax + output + loss. No intermediate global traffic.
__global__ __launch_bounds__(256) void vq_fused(
    const float* __restrict__ x, const float* __restrict__ cb,
    const unsigned short* __restrict__ cbb, const float* __restrict__ cnorm,
    float* __restrict__ out, float* __restrict__ loss_acc)
{
    __shared__ unsigned short xs[TOKB * D_DIM];              // 32768 B, persistent bf16(2x)
    __shared__ union {
        unsigned short cs[TN * DBLK];                        // 32768 B (staging)
        float sc[32 * 257];                                  // 32896 B (score rounds)
        struct {                                             // epilogue (19712 B)
            float ms[32 * 65]; int mi[32 * 65];
            int tki[32 * TOPK]; float tks[32 * TOPK]; float tkw[32 * TOPK];
        } mg;
    } u;
    __shared__ float redbuf[4];

    const int t    = threadIdx.x;
    const int lane = t & 63;
    const int w    = t >> 6;
    const int m32  = lane & 31;
    const int half = lane >> 5;
    const int tok0 = blockIdx.x * TOKB;

    // ---- stage x tile once: fp32 -> bf16(2x), XOR-swizzled row layout ----
    // row r, 64 granules of 16B; slot gp holds global granule (gp&56)|((gp&7)^(r&7))
    #pragma unroll
    for (int i = 0; i < 8; ++i) {
        const int s = i * 256 + t, row = s >> 6, gp = s & 63;
        const int g = (gp & 56) | ((gp & 7) ^ (row & 7));
        const float4* src = (const float4*)&x[(size_t)(tok0 + row) * D_DIM + g * 8];
        float4 v0 = src[0], v1 = src[1];
        ushort4 o0, o1;
        o0.x = f2bf(2.f*v0.x); o0.y = f2bf(2.f*v0.y); o0.z = f2bf(2.f*v0.z); o0.w = f2bf(2.f*v0.w);
        o1.x = f2bf(2.f*v1.x); o1.y = f2bf(2.f*v1.y); o1.z = f2bf(2.f*v1.z); o1.w = f2bf(2.f*v1.w);
        *(ushort4*)&xs[s * 8]     = o0;
        *(ushort4*)&xs[s * 8 + 4] = o1;
    }

    // persistent top-8: thread owns (token = t&31, column slice sub = t>>5)
    const int stok = t & 31, ssub = t >> 5;
    float ts[8]; int ti[8];
    init8(ts, ti);

    for (int chunk = 0; chunk < NCHUNK; ++chunk) {
        const int cbase = chunk * TN;
        // cnorm for this wave's two column blocks (C/D layout: col = lane&31)
        const float cn0 = cnorm[cbase + w * 64 + m32];
        const float cn1 = cnorm[cbase + w * 64 + 32 + m32];

        f32x16 acc0, acc1;
        #pragma unroll
        for (int i = 0; i < 16; ++i) { acc0[i] = 0.f; acc1[i] = 0.f; }

        for (int db = 0; db < NDBLK; ++db) {
            const int dbase = db * DBLK;
            __syncthreads();   // prior cs/sc consumers done (also covers x-stage on entry)
            // codebook slice [256][64] async -> LDS, swizzled on the global side
            #pragma unroll
            for (int i = 0; i < 8; ++i) {
                const int s = i * 256 + t, row = s >> 3, gp = s & 7;
                const int g = gp ^ (row & 7);
                gl_lds16(&cbb[(size_t)(cbase + row) * D_DIM + dbase + g * 8], &u.cs[s * 8]);
            }
            __syncthreads();   // DMA drained
            #pragma unroll
            for (int ks = 0; ks < 4; ++ks) {
                const int gfrag = db * 8 + ks * 2 + half;          // x granule index
                const int aslot = (gfrag & 56) | ((gfrag & 7) ^ (m32 & 7));
                bf16x8 a = *(const bf16x8*)&xs[m32 * D_DIM + aslot * 8];
                const int gsw = ((ks * 2 + half) ^ (m32 & 7)) * 8;
                bf16x8 b0 = *(const bf16x8*)&u.cs[(w * 64 + m32) * 64 + gsw];
                bf16x8 b1 = *(const bf16x8*)&u.cs[(w * 64 + 32 + m32) * 64 + gsw];
                acc0 = __builtin_amdgcn_mfma_f32_32x32x16_bf16(a, b0, acc0, 0, 0, 0);
                acc1 = __builtin_amdgcn_mfma_f32_32x32x16_bf16(a, b1, acc1, 0, 0, 0);
            }
        }
        __syncthreads();   // all MFMAs done; cs dead -> reuse as score buffer
        #pragma unroll
        for (int r = 0; r < 16; ++r) {
            const int row32 = (r & 3) + 8 * (r >> 2) + 4 * half;   // C/D layout (m74/m101)
            u.sc[row32 * 257 + w * 64 + m32]      = acc0[r] - cn0;
            u.sc[row32 * 257 + w * 64 + 32 + m32] = acc1[r] - cn1;
        }
        __syncthreads();
        // scan this chunk's 32-col slice into the persistent list (ascending index order)
        const int jb = ssub * 32;
        for (int j = 0; j < 32; ++j)
            ins8(u.sc[stok * 257 + jb + j], cbase + jb + j, ts, ti);
        // next chunk's loop-top barrier separates this scan from cs restaging
    }

    // ---- epilogue (all in-block) ----
    __syncthreads();
    #pragma unroll
    for (int e = 0; e < 8; ++e) {     // dump 8 partial lists per token
        u.mg.ms[stok * 65 + ssub * 8 + e] = ts[e];
        u.mg.mi[stok * 65 + ssub * 8 + e] = ti[e];
    }
    __syncthreads();
    if (t < TOKB) {   // merge 8 lists -> global top-8 (lists fed in sub order)
        float bs[8]; int bi[8]; init8(bs, bi);
        #pragma unroll 4
        for (int k = 0; k < 64; ++k)
            ins8(u.mg.ms[t * 65 + k], u.mg.mi[t * 65 + k], bs, bi);
        #pragma unroll
        for (int r = 0; r < TOPK; ++r) u.mg.tki[t * TOPK + r] = bi[r];
    }
    __syncthreads();
    {   // exact fp32 rescore: one (token, entry) dot per thread
        const int token = t >> 3, e = t & 7;
        const int idx = u.mg.tki[token * TOPK + e];
        const float4* xr = (const float4*)(x + (size_t)(tok0 + token) * D_DIM);
        const float4* cr = (const float4*)(cb + (size_t)idx * D_DIM);
        float dot = 0.f;
        #pragma unroll 4
        for (int i = 0; i < D_DIM / 4; ++i) {
            float4 xv = xr[i], cv = cr[i];
            dot += xv.x*cv.x + xv.y*cv.y + xv.z*cv.z + xv.w*cv.w;
        }
        u.mg.tks[token * TOPK + e] = 2.f * dot - cnorm[idx];
    }
    __syncthreads();
    if (t < TOKB) {   // softmax over the 8
        float m = -1e38f;
        #pragma unroll
        for (int e = 0; e < TOPK; ++e) m = fmaxf(m, u.mg.tks[t*TOPK+e]);
        float sum = 0.f, wv[TOPK];
        #pragma unroll
        for (int e = 0; e < TOPK; ++e) { wv[e] = __expf(u.mg.tks[t*TOPK+e] - m); sum += wv[e]; }
        const float inv = 1.f / sum;
        #pragma unroll
        for (int e = 0; e < TOPK; ++e) u.mg.tkw[t*TOPK+e] = wv[e] * inv;
    }
    __syncthreads();
    // output + loss partial
    float lsum = 0.f;
    #pragma unroll 1
    for (int it = 0; it < (TOKB * (D_DIM / 4)) / 256; ++it) {   // 16 iters
        const int p = it * 256 + t;
        const int token = p >> 7, d4 = p & 127;
        float4 q = {0.f, 0.f, 0.f, 0.f};
        #pragma unroll
        for (int e = 0; e < TOPK; ++e) {
            const float wv = u.mg.tkw[token * TOPK + e];
            const int  idx = u.mg.tki[token * TOPK + e];
            const float4 cv = ((const float4*)cb)[(size_t)idx * (D_DIM / 4) + d4];
            q.x += wv * cv.x; q.y += wv * cv.y; q.z += wv * cv.z; q.w += wv * cv.w;
        }
        const size_t go = (size_t)(tok0 + token) * (D_DIM / 4) + d4;
        const float4 xv = ((const float4*)x)[go];
        const float ex = q.x - xv.x, ey = q.y - xv.y, ez = q.z - xv.z, ew = q.w - xv.w;
        lsum += ex*ex + ey*ey + ez*ez + ew*ew;
        ((float4*)out)[go] = q;   // STE output == quantized value
    }
    #pragma unroll
    for (int off = 32; off > 0; off >>= 1) lsum += __shfl_down(lsum, off, 64);
    if (lane == 0) redbuf[w] = lsum;
    __syncthreads();
    if (t == 0) atomicAdd(loss_acc, redbuf[0] + redbuf[1] + redbuf[2] + redbuf[3]);
}

__global__ void finalize_kernel(const float* __restrict__ loss_acc,
                                float* __restrict__ out) {
    out[(size_t)N_TOK * D_DIM] = 1.25f * loss_acc[0] / (float)((size_t)N_TOK * D_DIM);
}

extern "C" void kernel_launch(void* const* d_in, const int* in_sizes, int n_in,
                              void* d_out, int out_size, void* d_ws, size_t ws_size,
                              hipStream_t stream) {
    const float* x  = (const float*)d_in[0];   // [8,2048,512] fp32
    const float* cb = (const float*)d_in[1];   // [4096,512] fp32
    float* out = (float*)d_out;

    char* ws = (char*)d_ws;
    unsigned short* cbb   = (unsigned short*)ws;            // 4 MB
    float*          cnorm = (float*)(ws + 4194304);         // 16 KB
    float*          loss  = (float*)(ws + 4210688);         // 4 B

    conv_cb_kernel<<<4096, 64, 0, stream>>>(cb, cbb, cnorm, loss);
    vq_fused<<<N_TOK / TOKB, 256, 0, stream>>>(x, cb, cbb, cnorm, out, loss);
    finalize_kernel<<<1, 1, 0, stream>>>(loss, out);
}

// Round 4
// 286.351 us; speedup vs baseline: 2.8720x; 1.6973x over previous
//
#include <hip/hip_runtime.h>
#include <hip/hip_bf16.h>
#include <stdint.h>

// Problem constants
#define D_DIM 512
#define K_CB  4096
#define N_TOK 16384
#define TOPK  8

// Fused kernel: 32 tokens per block, full 4096 centroids in 16 passes of 256
#define TOKB  32
#define NPASS 16

typedef __attribute__((ext_vector_type(8)))  short bf16x8;
typedef __attribute__((ext_vector_type(16))) float f32x16;

__device__ __forceinline__ unsigned short f2bf(float f) {
    union { float f; unsigned u; } v; v.f = f;
    unsigned r = (v.u + 0x7fffu + ((v.u >> 16) & 1u)) >> 16;  // RNE
    return (unsigned short)r;
}

// sortable key: 20 high bits = order-preserving float map, 12 low bits = 4095-idx
// => unique keys; max-order == (score desc, idx asc) == jax top_k tie-break
__device__ __forceinline__ unsigned int mkkey(float s, unsigned int idxc) {
    unsigned int u = __float_as_uint(s);
    unsigned int k = u ^ ((unsigned int)((int)u >> 31) | 0x80000000u);
    return (k & 0xFFFFF000u) | idxc;
}

// branchless top-8 insert: 8x (v_max_u32 + v_min_u32), no divergence
__device__ __forceinline__ void inskey(unsigned int k, unsigned int (&ts)[8]) {
    #pragma unroll
    for (int q = 0; q < 8; ++q) {
        unsigned int hi = ts[q] > k ? ts[q] : k;
        unsigned int lo = ts[q] > k ? k : ts[q];
        ts[q] = hi; k = lo;
    }
}

// cbf = bf16(codebook) in MFMA-A-fragment order; cnorm = ||c||^2 fp32.
// Fragment order: elem(R=row/32, ks, lane=(h<<5)|(row&31), j) so a wave's
// A-frag load (lane -> 16B) is one fully-coalesced global_load_dwordx4.
__global__ void conv_cb_kernel(const float* __restrict__ cb,
                               unsigned short* __restrict__ cbf,
                               float* __restrict__ cnorm,
                               float* __restrict__ loss) {
    const int row = blockIdx.x;
    const int t = threadIdx.x;          // 64 threads: t = (ks<<1)|h
    if (row == 0 && t == 0) *loss = 0.f;
    const float* src = cb + (size_t)row * D_DIM + (t >> 1) * 16 + (t & 1) * 8;
    float4 a = ((const float4*)src)[0], b = ((const float4*)src)[1];
    ushort4 o0, o1;
    o0.x = f2bf(a.x); o0.y = f2bf(a.y); o0.z = f2bf(a.z); o0.w = f2bf(a.w);
    o1.x = f2bf(b.x); o1.y = f2bf(b.y); o1.z = f2bf(b.z); o1.w = f2bf(b.w);
    const size_t di = (size_t)(row >> 5) * 16384 + (size_t)(t >> 1) * 512
                    + (size_t)((((t & 1) << 5) + (row & 31)) * 8);
    *(ushort4*)(cbf + di)     = o0;
    *(ushort4*)(cbf + di + 4) = o1;
    float sq = a.x*a.x + a.y*a.y + a.z*a.z + a.w*a.w
             + b.x*b.x + b.y*b.y + b.z*b.z + b.w*b.w;
    #pragma unroll
    for (int off = 32; off > 0; off >>= 1) sq += __shfl_down(sq, off, 64);
    if (t == 0) cnorm[row] = sq;
}

// Fused: A = centroids (coalesced global, fragment-ordered), B = tokens (LDS,
// XOR-swizzled), selection on accumulator registers via packed keys.
// K-loop is barrier-free.
__global__ __launch_bounds__(256) void vq_fused(
    const float* __restrict__ x, const float* __restrict__ cb,
    const unsigned short* __restrict__ cbf, const float* __restrict__ cnorm,
    float* __restrict__ out, float* __restrict__ loss_acc)
{
    __shared__ union {
        unsigned short xs[TOKB * D_DIM];                 // 32768 B: bf16(2x), swizzled
        struct {                                         // epilogue (11392 B)
            unsigned int keys[TOKB * 65];
            int tki[TOKB * TOPK]; float tks[TOKB * TOPK]; float tkw[TOKB * TOPK];
        } mg;
    } u;
    __shared__ float ncn[K_CB];                          // 16384 B: -||c||^2
    __shared__ float redbuf[4];

    const int t    = threadIdx.x;
    const int lane = t & 63;
    const int w    = t >> 6;
    const int m32  = lane & 31;
    const int half = lane >> 5;
    const int tok0 = blockIdx.x * TOKB;

    // ---- stage xs = bf16(2x) (XOR-swizzled granules) + ncn = -cnorm ----
    #pragma unroll
    for (int i = 0; i < 8; ++i) {
        const int s = i * 256 + t, row = s >> 6, gp = s & 63;
        const int g = (gp & 56) | ((gp & 7) ^ (row & 7));
        const float4* src = (const float4*)&x[(size_t)(tok0 + row) * D_DIM + g * 8];
        float4 v0 = src[0], v1 = src[1];
        ushort4 o0, o1;
        o0.x = f2bf(2.f*v0.x); o0.y = f2bf(2.f*v0.y); o0.z = f2bf(2.f*v0.z); o0.w = f2bf(2.f*v0.w);
        o1.x = f2bf(2.f*v1.x); o1.y = f2bf(2.f*v1.y); o1.z = f2bf(2.f*v1.z); o1.w = f2bf(2.f*v1.w);
        *(ushort4*)&u.xs[s * 8]     = o0;
        *(ushort4*)&u.xs[s * 8 + 4] = o1;
    }
    #pragma unroll
    for (int i = 0; i < 4; ++i) {
        const int s = i * 256 + t;
        float4 v = ((const float4*)cnorm)[s];
        float4 nv = {-v.x, -v.y, -v.z, -v.w};
        *(float4*)&ncn[s * 4] = nv;
    }
    __syncthreads();

    // persistent top-8 keys for token (tok0 + m32); halves/waves hold partial lists
    unsigned int ts[8];
    #pragma unroll
    for (int i = 0; i < 8; ++i) ts[i] = 0u;

    const char* cf = (const char*)cbf;
    const int xbase = m32 * D_DIM;

    for (int pass = 0; pass < NPASS; ++pass) {
        const int rowbase = pass * 256 + w * 64;     // this wave's 64 centroids
        // acc init = -cnorm (C/D rows r: (r&3) + 8*(r>>2) + 4*half)
        f32x16 acc0, acc1;
        #pragma unroll
        for (int g = 0; g < 4; ++g) {
            float4 v0 = *(const float4*)&ncn[rowbase +      g * 8 + 4 * half];
            float4 v1 = *(const float4*)&ncn[rowbase + 32 + g * 8 + 4 * half];
            acc0[g*4+0] = v0.x; acc0[g*4+1] = v0.y; acc0[g*4+2] = v0.z; acc0[g*4+3] = v0.w;
            acc1[g*4+0] = v1.x; acc1[g*4+1] = v1.y; acc1[g*4+2] = v1.z; acc1[g*4+3] = v1.w;
        }
        // barrier-free K loop: 2 coalesced A loads + 1 swizzled B read + 2 MFMA
        const unsigned int abase = (unsigned int)(rowbase >> 5) * 32768u
                                 + (unsigned int)lane * 16u;
        #pragma unroll 4
        for (int ks = 0; ks < 32; ++ks) {
            bf16x8 A0 = *(const bf16x8*)(cf + abase + ks * 1024);
            bf16x8 A1 = *(const bf16x8*)(cf + abase + 32768 + ks * 1024);
            const int gf = ks * 2 + half;
            const int slot = (gf & 56) | ((gf & 7) ^ (m32 & 7));
            bf16x8 B = *(const bf16x8*)&u.xs[xbase + slot * 8];
            acc0 = __builtin_amdgcn_mfma_f32_32x32x16_bf16(A0, B, acc0, 0, 0, 0);
            acc1 = __builtin_amdgcn_mfma_f32_32x32x16_bf16(A1, B, acc1, 0, 0, 0);
        }
        // register-resident selection (branchless, unique keys => order-free)
        const unsigned int K0 = (unsigned int)(4095 - rowbase - 4 * half);
        #pragma unroll
        for (int r = 0; r < 16; ++r) {
            const unsigned int cr = (unsigned int)((r & 3) + 8 * (r >> 2));
            inskey(mkkey(acc0[r], K0 - cr), ts);
        }
        #pragma unroll
        for (int r = 0; r < 16; ++r) {
            const unsigned int cr = (unsigned int)((r & 3) + 8 * (r >> 2));
            inskey(mkkey(acc1[r], K0 - 32u - cr), ts);
        }
    }

    // ---- epilogue ----
    __syncthreads();   // xs dead -> reuse as mg
    #pragma unroll
    for (int e = 0; e < 8; ++e)
        u.mg.keys[m32 * 65 + (w * 2 + half) * 8 + e] = ts[e];
    __syncthreads();
    if (t < TOKB) {    // merge 8 partial lists -> global top-8, decode indices
        unsigned int bs[8];
        #pragma unroll
        for (int i = 0; i < 8; ++i) bs[i] = 0u;
        #pragma unroll 4
        for (int k = 0; k < 64; ++k) inskey(u.mg.keys[t * 65 + k], bs);
        #pragma unroll
        for (int r = 0; r < TOPK; ++r)
            u.mg.tki[t * TOPK + r] = 4095 - (int)(bs[r] & 0xFFFu);
    }
    __syncthreads();
    {   // exact fp32 rescore: one (token, entry) dot per thread
        const int token = t >> 3, e = t & 7;
        const int idx = u.mg.tki[token * TOPK + e];
        const float4* xr = (const float4*)(x + (size_t)(tok0 + token) * D_DIM);
        const float4* cr = (const float4*)(cb + (size_t)idx * D_DIM);
        float dot = 0.f;
        #pragma unroll 4
        for (int i = 0; i < D_DIM / 4; ++i) {
            float4 xv = xr[i], cv = cr[i];
            dot += xv.x*cv.x + xv.y*cv.y + xv.z*cv.z + xv.w*cv.w;
        }
        u.mg.tks[token * TOPK + e] = 2.f * dot - cnorm[idx];
    }
    __syncthreads();
    if (t < TOKB) {    // softmax over the 8 (== renormalized full softmax on top-8)
        float m = -1e38f;
        #pragma unroll
        for (int e = 0; e < TOPK; ++e) m = fmaxf(m, u.mg.tks[t*TOPK+e]);
        float sum = 0.f, wv[TOPK];
        #pragma unroll
        for (int e = 0; e < TOPK; ++e) { wv[e] = __expf(u.mg.tks[t*TOPK+e] - m); sum += wv[e]; }
        const float inv = 1.f / sum;
        #pragma unroll
        for (int e = 0; e < TOPK; ++e) u.mg.tkw[t*TOPK+e] = wv[e] * inv;
    }
    __syncthreads();
    // output + loss partial
    float lsum = 0.f;
    #pragma unroll 1
    for (int it = 0; it < (TOKB * (D_DIM / 4)) / 256; ++it) {   // 16 iters
        const int p = it * 256 + t;
        const int token = p >> 7, d4 = p & 127;
        float4 q = {0.f, 0.f, 0.f, 0.f};
        #pragma unroll
        for (int e = 0; e < TOPK; ++e) {
            const float wv = u.mg.tkw[token * TOPK + e];
            const int  idx = u.mg.tki[token * TOPK + e];
            const float4 cv = ((const float4*)cb)[(size_t)idx * (D_DIM / 4) + d4];
            q.x += wv * cv.x; q.y += wv * cv.y; q.z += wv * cv.z; q.w += wv * cv.w;
        }
        const size_t go = (size_t)(tok0 + token) * (D_DIM / 4) + d4;
        const float4 xv = ((const float4*)x)[go];
        const float ex = q.x - xv.x, ey = q.y - xv.y, ez = q.z - xv.z, ew = q.w - xv.w;
        lsum += ex*ex + ey*ey + ez*ez + ew*ew;
        ((float4*)out)[go] = q;   // STE output == quantized value
    }
    #pragma unroll
    for (int off = 32; off > 0; off >>= 1) lsum += __shfl_down(lsum, off, 64);
    if (lane == 0) redbuf[w] = lsum;
    __syncthreads();
    if (t == 0) atomicAdd(loss_acc, redbuf[0] + redbuf[1] + redbuf[2] + redbuf[3]);
}

__global__ void finalize_kernel(const float* __restrict__ loss_acc,
                                float* __restrict__ out) {
    out[(size_t)N_TOK * D_DIM] = 1.25f * loss_acc[0] / (float)((size_t)N_TOK * D_DIM);
}

extern "C" void kernel_launch(void* const* d_in, const int* in_sizes, int n_in,
                              void* d_out, int out_size, void* d_ws, size_t ws_size,
                              hipStream_t stream) {
    const float* x  = (const float*)d_in[0];   // [8,2048,512] fp32
    const float* cb = (const float*)d_in[1];   // [4096,512] fp32
    float* out = (float*)d_out;

    char* ws = (char*)d_ws;
    unsigned short* cbf   = (unsigned short*)ws;            // 4 MB, fragment-ordered
    float*          cnorm = (float*)(ws + 4194304);         // 16 KB
    float*          loss  = (float*)(ws + 4210688);         // 4 B

    conv_cb_kernel<<<4096, 64, 0, stream>>>(cb, cbf, cnorm, loss);
    vq_fused<<<N_TOK / TOKB, 256, 0, stream>>>(x, cb, cbf, cnorm, out, loss);
    finalize_kernel<<<1, 1, 0, stream>>>(loss, out);
}